// Round 14
// baseline (161.890 us; speedup 1.0000x reference)
//
#include <hip/hip_runtime.h>

#define NN 3072
#define CCC 16
#define HH 128
#define KTOP 4
#define NCLS 455   // C(15,3)
#define EPSF 1e-5f

// ---------------- ws layout (float offsets) ----------------
#define OFF_F       0
#define SZ_F        (16*NCLS*HH)            // 931840
#define OFF_CNT     (OFF_F + SZ_F)
#define SZ_CNT      (16*NCLS)
#define OFF_SUMS    (OFF_CNT + SZ_CNT)
#define SZ_SUMS     32
#define OFF_NCNT    (OFF_SUMS + SZ_SUMS)    // int nodeCnt[16*16]
#define SZ_NCNT     256
#define SMALL_ZERO  (SZ_CNT + SZ_SUMS + SZ_NCNT)  // cnt+sums+nodeCnt (zeroed by k_fused blk0)
#define OFF_COLS    (OFF_NCNT + SZ_NCNT)
#define SZ_E        (NN*KTOP)
#define OFF_RANKS   (OFF_COLS + SZ_E)
#define OFF_FISEL   (OFF_RANKS + SZ_E)
#define OFF_NLIST   (OFF_FISEL + SZ_E)
#define SZ_NLIST    (16*NN)
#define OFF_AGG     (OFF_NLIST + SZ_NLIST)
#define OFF_HC      (OFF_AGG + SZ_F)
#define SZ_HC       (NN*KTOP*HH)
#define OFF_HALF    (OFF_HC + SZ_HC)
#define HOFF_WLH    0
#define HOFF_WRH    262144

#define MT 64              // rows per block for k_hc2
#define FTH 768            // k_fused threads (12 waves)
#define FMT 192            // rows per block for k_fused (12 nodes)
#define FBLK (NN*CCC/FMT)  // 256 blocks = exactly 1 per CU
#define GCP 8              // k_graph cols per block
#define GCB (HH/GCP)
#define W1P 132            // padded row stride (f16) for W1 LDS: 2-way bank aliasing only

typedef _Float16 h8 __attribute__((ext_vector_type(8)));
typedef float    f4 __attribute__((ext_vector_type(4)));

__device__ __forceinline__ int C2i(int x){ return x*(x-1)/2; }
__device__ __forceinline__ int C3i(int x){ return x*(x-1)*(x-2)/6; }

// ===== stage A+B fused: 768 thr / 192 rows per block, grid=256 (R13-proven) =====
__global__ __launch_bounds__(FTH) void k_fused(const float* __restrict__ X,
    const float* __restrict__ W1,
    const float* __restrict__ b1, const float* __restrict__ ln_g,
    const float* __restrict__ ln_b, const float* __restrict__ W2,
    const float* __restrict__ b2,
    const float* __restrict__ Wl, const float* __restrict__ Wr,
    _Float16* __restrict__ hbase, float* __restrict__ F, float* __restrict__ ws,
    int* __restrict__ cols, int* __restrict__ ranks, float* __restrict__ fiSel){
  __shared__ _Float16 w1h_s[HH*W1P];
  __shared__ _Float16 w1l_s[HH*W1P];
  __shared__ float llog[FMT];
  int t = threadIdx.x;
  int w = t >> 6;              // wave 0..11 -> rows 16w..16w+15 (node w)
  int lane = t & 63;
  int l15 = lane & 15, quad = lane >> 4;
  int base = blockIdx.x * FMT;
  int mA = base + 16*w + l15;

  // ---- X rows first: HBM latency hides under the W1-cvt loop below ----
  const float* xrow = X + (size_t)mA*HH;
  float4 xu[4], xv[4];
  #pragma unroll
  for (int c=0;c<4;++c){
    xu[c] = *(const float4*)(xrow + c*32 + quad*8);
    xv[c] = *(const float4*)(xrow + c*32 + quad*8 + 4);
  }

  // ---- W1 -> LDS f16 hi/lo (22 iters/thread) ----
  for (int j = t; j < HH*HH; j += FTH){
    int r = j >> 7, c0 = j & 127;
    float x = W1[j];
    _Float16 h = (_Float16)x;
    w1h_s[r*W1P + c0] = h;
    w1l_s[r*W1P + c0] = (_Float16)(x - (float)h);
  }

  // ---- folded housekeeping: zero F + cvt Wl/Wr + (blk 0) small zeros ----
  {
    f4 z4 = (f4){0.f,0.f,0.f,0.f};
    for (int i = blockIdx.x*FTH + t; i < SZ_F/4; i += FBLK*FTH)
      *(f4*)(F + (size_t)i*4) = z4;
    for (int i = blockIdx.x*FTH + t; i < 2*262144; i += FBLK*FTH){
      if (i < 262144) hbase[HOFF_WLH + i] = (_Float16)Wl[i];
      else            hbase[HOFF_WRH + (i-262144)] = (_Float16)Wr[i-262144];
    }
    if (blockIdx.x == 0)
      for (int i = t; i < SMALL_ZERO; i += FTH) ws[OFF_CNT + i] = 0.f;
  }

  // ---- phase 1: z=relu(X@W1^T+b1); LN; logit=zn.W2+b2 (identical math) ----
  h8 ah[4], al[4];
  #pragma unroll
  for (int c=0;c<4;++c){
    float xvv[8] = {xu[c].x,xu[c].y,xu[c].z,xu[c].w,xv[c].x,xv[c].y,xv[c].z,xv[c].w};
    #pragma unroll
    for (int j=0;j<8;++j){
      _Float16 hi = (_Float16)xvv[j];
      ah[c][j] = hi;
      al[c][j] = (_Float16)(xvv[j] - (float)hi);
    }
  }
  __syncthreads();   // W1 LDS ready

  f4 acc[8];
  #pragma unroll
  for (int nt=0;nt<8;++nt) acc[nt] = (f4){0.f,0.f,0.f,0.f};

  #pragma unroll
  for (int c=0;c<4;++c){
    #pragma unroll
    for (int nt=0;nt<8;++nt){
      int o = nt*16 + l15;
      h8 bh  = *(const h8*)(w1h_s + o*W1P + c*32 + quad*8);
      h8 bl_ = *(const h8*)(w1l_s + o*W1P + c*32 + quad*8);
      acc[nt] = __builtin_amdgcn_mfma_f32_16x16x32_f16(ah[c], bh,  acc[nt], 0,0,0);
      acc[nt] = __builtin_amdgcn_mfma_f32_16x16x32_f16(al[c], bh,  acc[nt], 0,0,0);
      acc[nt] = __builtin_amdgcn_mfma_f32_16x16x32_f16(ah[c], bl_, acc[nt], 0,0,0);
      acc[nt] = __builtin_amdgcn_mfma_f32_16x16x32_f16(al[c], bl_, acc[nt], 0,0,0);
    }
  }

  float bv[8], gv[8], lv[8], wv[8];
  #pragma unroll
  for (int nt=0;nt<8;++nt){
    int o = nt*16 + l15;
    bv[nt]=b1[o]; gv[nt]=ln_g[o]; lv[nt]=ln_b[o]; wv[nt]=W2[o];
  }
  float b2v = b2[0];
  #pragma unroll
  for (int r=0;r<4;++r){
    float z[8];
    float s1=0.f, s2=0.f;
    #pragma unroll
    for (int nt=0;nt<8;++nt){
      float zz = acc[nt][r] + bv[nt];
      zz = zz>0.f ? zz : 0.f;
      z[nt] = zz; s1 += zz; s2 += zz*zz;
    }
    #pragma unroll
    for (int m=1;m<16;m<<=1){ s1 += __shfl_xor(s1,m); s2 += __shfl_xor(s2,m); }
    float mu = s1/(float)HH;
    float var = s2/(float)HH - mu*mu;
    float rs = 1.0f/sqrtf(var+EPSF);
    float s3 = 0.f;
    #pragma unroll
    for (int nt=0;nt<8;++nt){
      float zn = (z[nt]-mu)*rs*gv[nt] + lv[nt];
      s3 += zn*wv[nt];
    }
    #pragma unroll
    for (int m=1;m<16;m<<=1) s3 += __shfl_xor(s3,m);
    if (l15 == 0) llog[16*w + quad*4 + r] = s3 + b2v;
  }
  __syncthreads();

  // ---- phase 2: topk/softmax per node (threads 0..11), plain stores only ----
  if (t < FMT/16){
    int n = blockIdx.x*(FMT/16) + t;
    float l[CCC];
    #pragma unroll
    for (int c=0;c<CCC;++c) l[c] = llog[t*16+c];
    unsigned mask = 0;
    #pragma unroll
    for (int k=0;k<KTOP;++k){
      float best = -3e38f; int bi = 0;
      #pragma unroll
      for (int c=0;c<CCC;++c){
        bool taken = (mask>>c)&1u;
        if (!taken && l[c] > best){ best = l[c]; bi = c; }
      }
      mask |= 1u<<bi;
    }
    float m = -3e38f;
    #pragma unroll
    for (int c=0;c<CCC;++c) m = l[c]>m ? l[c] : m;
    float s = 0.f;
    #pragma unroll
    for (int c=0;c<CCC;++c) s += expf(l[c]-m);
    float inv = 1.0f/s;
    unsigned m2 = mask;
    for (int j=0;j<KTOP;++j){
      int ci = __ffs(m2)-1; m2 &= m2-1u;
      unsigned rest = mask & ~(1u<<ci);
      int v[3]; unsigned r2 = rest;
      #pragma unroll
      for (int q=0;q<3;++q){ int col = __ffs(r2)-1; r2 &= r2-1u; v[q] = col - (col>ci ? 1:0); }
      int rank = C3i(v[2]) + C2i(v[1]) + v[0];
      int e4 = n*KTOP + j;
      cols[e4] = ci; ranks[e4] = rank; fiSel[e4] = expf(l[ci]-m)*inv;
    }
  }
}

// ===== stage C: nodeList build in blocks 0..11 (FRONT, overlaps the long tail),
// ===== then class feature sums (high-TLP atomics) in blocks 12..6155 =====
__global__ __launch_bounds__(256) void k_accF(const float* __restrict__ X,
    const int* __restrict__ cols, const int* __restrict__ ranks,
    const float* __restrict__ fiSel, float* __restrict__ F, float* __restrict__ cnt,
    int* __restrict__ nodeCnt, int* __restrict__ nodeList){
  __shared__ int lcnt[CCC];
  __shared__ int lbase[CCC];
  int t = threadIdx.x;
  if (blockIdx.x < 12){
    int nb = blockIdx.x;   // 0..11
    if (t < CCC) lcnt[t] = 0;
    __syncthreads();
    int n = nb*256 + t;
    int mycis[KTOP], mypos[KTOP];
    #pragma unroll
    for (int j=0;j<KTOP;++j){
      int ci = cols[n*KTOP+j];
      mycis[j] = ci;
      mypos[j] = atomicAdd(&lcnt[ci], 1);
    }
    __syncthreads();
    if (t < CCC) lbase[t] = atomicAdd(&nodeCnt[t*16], lcnt[t]);
    __syncthreads();
    #pragma unroll
    for (int j=0;j<KTOP;++j){
      int ci = mycis[j];
      nodeList[ci*NN + lbase[ci] + mypos[j]] = n*KTOP + j;
    }
  } else {
    int e = (blockIdx.x-12)*2 + (t>>7);
    int h = t & 127;
    int ci = cols[e], rank = ranks[e];
    float fi = fiSel[e];
    int n = e >> 2;
    float v = X[(n*CCC+ci)*HH + h] * fi;
    atomicAdd(&F[(ci*NCLS+rank)*HH + h], v);
    if (h==0) atomicAdd(&cnt[ci*NCLS+rank], 1.0f);
  }
}

// ====== stage D: pairs + singles + degrees + inclusion-exclusion agg (R1-proven) ======
__global__ __launch_bounds__(256) void k_graph(const float* __restrict__ F,
    const float* __restrict__ cnt, float* __restrict__ agg){
  int cb = blockIdx.x, ci = blockIdx.y, t = threadIdx.x;
  __shared__ float cntl[NCLS];
  __shared__ float PcS[105], UcS[15];
  __shared__ int   abcs[NCLS];   // a | b<<5 | c<<10
  __shared__ int   prs[NCLS];    // pab | pac<<10 | pbc<<20
  __shared__ float Fl[NCLS*GCP];
  __shared__ float P[105*GCP];
  __shared__ float U[15*GCP];
  const float* Fc = F + (size_t)ci*NCLS*HH + cb*GCP;

  for (int i=t; i<NCLS*2; i+=256){
    int r = i>>1, hf = i&1;
    float4 v = *(const float4*)(Fc + (size_t)r*HH + hf*4);
    *(float4*)(&Fl[r*GCP + hf*4]) = v;
  }
  for (int r=t; r<NCLS; r+=256){
    cntl[r] = cnt[ci*NCLS+r];
    int c=2; while (c<14 && C3i(c+1)<=r) c++;
    int rem = r - C3i(c);
    int b=1; while (b<c-1 && C2i(b+1)<=rem) b++;
    int a = rem - C2i(b);
    abcs[r] = a | (b<<5) | (c<<10);
    prs[r] = (C2i(b)+a) | ((C2i(c)+a)<<10) | ((C2i(c)+b)<<20);
  }
  __syncthreads();
  if (t<105){
    int pb=1; while (pb<14 && C2i(pb+1)<=t) pb++;
    int pa = t - C2i(pb);
    float s=0.f;
    #pragma unroll
    for (int z=0;z<15;++z){
      if (z==pa||z==pb) continue;
      int lo,mid,hi;
      if (z<pa){lo=z;mid=pa;hi=pb;} else if (z<pb){lo=pa;mid=z;hi=pb;} else {lo=pa;mid=pb;hi=z;}
      s += cntl[C3i(hi)+C2i(mid)+lo];
    }
    PcS[t]=s;
  }
  __syncthreads();
  if (t<15){
    float s=0.f;
    #pragma unroll
    for (int y=0;y<15;++y){
      if (y==t) continue;
      int lo = t<y?t:y, hi = t<y?y:t;
      s += PcS[C2i(hi)+lo];
    }
    UcS[t]=0.5f*s;
  }
  __syncthreads();
  for (int idx=t; idx<105*GCP; idx+=256){
    int p = idx/GCP, col = idx&(GCP-1);
    int pb=1; while (pb<14 && C2i(pb+1)<=p) pb++;
    int pa = p - C2i(pb);
    float s=0.f;
    #pragma unroll
    for (int z=0;z<15;++z){
      if (z==pa||z==pb) continue;
      int lo,mid,hi;
      if (z<pa){lo=z;mid=pa;hi=pb;} else if (z<pb){lo=pa;mid=z;hi=pb;} else {lo=pa;mid=pb;hi=z;}
      s += Fl[(C3i(hi)+C2i(mid)+lo)*GCP + col];
    }
    P[idx]=s;
  }
  __syncthreads();
  for (int idx=t; idx<15*GCP; idx+=256){
    int x = idx/GCP, col = idx&(GCP-1);
    float s=0.f;
    #pragma unroll
    for (int y=0;y<15;++y){
      if (y==x) continue;
      int lo = x<y?x:y, hi = x<y?y:x;
      s += P[(C2i(hi)+lo)*GCP + col];
    }
    U[idx]=0.5f*s;
  }
  __syncthreads();
  for (int idx=t; idx<NCLS*GCP; idx+=256){
    int r = idx/GCP, col = idx&(GCP-1);
    int v1=abcs[r]; int a=v1&31,b=(v1>>5)&31,c=(v1>>10)&31;
    int v2=prs[r];  int pab=v2&1023,pac=(v2>>10)&1023,pbc=(v2>>20)&1023;
    float deg = UcS[a]+UcS[b]+UcS[c]-PcS[pab]-PcS[pac]-PcS[pbc]+cntl[r];
    float invd = 1.0f/fmaxf(deg,1.0f);
    float v = U[a*GCP+col]+U[b*GCP+col]+U[c*GCP+col]
            - P[pab*GCP+col]-P[pac*GCP+col]-P[pbc*GCP+col]
            + Fl[r*GCP+col];
    agg[(size_t)ci*NCLS*HH + (size_t)r*HH + cb*GCP + col] = v*invd;
  }
}

// ===== stage E: hc = relu(agg[rank]@Wl^T + bl + fi*X @ Wr^T) =====
// 512 thr: waves 0-3 compute cols 0-63, waves 4-7 cols 64-127 of the SAME 64 rows
// -> 2x working waves/CU vs R13 (attacks gather-latency boundness). Math identical.
__global__ __launch_bounds__(512) void k_hc2(const float* __restrict__ X,
    const float* __restrict__ agg,
    const _Float16* __restrict__ Wlh, const _Float16* __restrict__ Wrh,
    const float* __restrict__ bl,
    const int* __restrict__ ranks, const float* __restrict__ fiSel,
    const int* __restrict__ nodeCnt, const int* __restrict__ nodeList,
    float* __restrict__ hcBuf, float* __restrict__ sums){
  int ci = blockIdx.y;
  int cntc = nodeCnt[ci*16];
  int base = blockIdx.x * MT;
  if (base >= cntc) return;
  __shared__ float rb[16];
  int t = threadIdx.x;
  int w = t >> 6;            // 0..7
  int wq = w & 3;            // row-group wave (16 rows each)
  int half = w >> 2;         // column half: nt base = half*4
  int lane = t & 63;
  int l15 = lane & 15, quad = lane >> 4;

  int pA = base + 16*wq + l15;
  float fi = 0.f; int nA = 0; int rkA = -1;
  if (pA < cntc){
    int e = nodeList[ci*NN + pA];
    fi = fiSel[e]; nA = e >> 2; rkA = ranks[e];
  }
  // A-operand 1: fi * X[nA, ci, :]
  const float* xrow = X + ((size_t)nA*CCC + ci)*HH;
  h8 af[4];
  #pragma unroll
  for (int c=0;c<4;++c){
    float4 u = *(const float4*)(xrow + c*32 + quad*8);
    float4 v = *(const float4*)(xrow + c*32 + quad*8 + 4);
    float xv[8] = {u.x,u.y,u.z,u.w,v.x,v.y,v.z,v.w};
    #pragma unroll
    for (int j=0;j<8;++j) af[c][j] = (_Float16)(xv[j]*fi);
  }
  // A-operand 2: agg[ci, rank(pA), :]  (zero for inactive rows)
  h8 ag[4];
  if (rkA >= 0){
    const float* arow = agg + ((size_t)ci*NCLS + rkA)*HH;
    #pragma unroll
    for (int c=0;c<4;++c){
      float4 u = *(const float4*)(arow + c*32 + quad*8);
      float4 v = *(const float4*)(arow + c*32 + quad*8 + 4);
      float xv[8] = {u.x,u.y,u.z,u.w,v.x,v.y,v.z,v.w};
      #pragma unroll
      for (int j=0;j<8;++j) ag[c][j] = (_Float16)xv[j];
    }
  } else {
    #pragma unroll
    for (int c=0;c<4;++c) ag[c] = (h8){0,0,0,0,0,0,0,0};
  }

  f4 acc[4];
  #pragma unroll
  for (int nt=0;nt<4;++nt) acc[nt] = (f4){0.f,0.f,0.f,0.f};

  const _Float16* WcR = Wrh + (size_t)ci*HH*HH;
  const _Float16* WcL = Wlh + (size_t)ci*HH*HH;
  #pragma unroll
  for (int c=0;c<4;++c){
    #pragma unroll
    for (int nt=0;nt<4;++nt){
      int o = (half*4 + nt)*16 + l15;
      h8 br = *(const h8*)(WcR + (size_t)o*HH + c*32 + quad*8);
      h8 blf= *(const h8*)(WcL + (size_t)o*HH + c*32 + quad*8);
      acc[nt] = __builtin_amdgcn_mfma_f32_16x16x32_f16(af[c], br,  acc[nt], 0,0,0);
      acc[nt] = __builtin_amdgcn_mfma_f32_16x16x32_f16(ag[c], blf, acc[nt], 0,0,0);
    }
  }

  float s1 = 0.f, s2 = 0.f;
  #pragma unroll
  for (int r=0;r<4;++r){
    int pD = base + 16*wq + quad*4 + r;
    int e2 = -1;
    if (pD < cntc) e2 = nodeList[ci*NN + pD];
    if (e2 >= 0){
      float* drow = hcBuf + (size_t)e2*HH;
      #pragma unroll
      for (int nt=0;nt<4;++nt){
        int o = (half*4 + nt)*16 + l15;
        float vv = acc[nt][r] + bl[ci*HH + o];
        vv = vv>0.f ? vv : 0.f;
        drow[o] = vv;
        s1 += vv; s2 += vv*vv;
      }
    }
  }
  #pragma unroll
  for (int m=1;m<64;m<<=1){ s1 += __shfl_xor(s1,m); s2 += __shfl_xor(s2,m); }
  if (lane == 0){ rb[w] = s1; rb[8+w] = s2; }
  __syncthreads();
  if (t==0){
    float a=0.f, b=0.f;
    #pragma unroll
    for (int i=0;i<8;++i){ a += rb[i]; b += rb[8+i]; }
    atomicAdd(&sums[ci], a);
    atomicAdd(&sums[16+ci], b);
  }
}

// ========== stage F: masked mean/var normalize, write output ==========
__global__ __launch_bounds__(256) void k_out(const float* __restrict__ hcBuf,
    const int* __restrict__ cols, const int* __restrict__ nodeCnt,
    const float* __restrict__ sums, float* __restrict__ out){
  int idx = blockIdx.x*256 + threadIdx.x;
  int e = idx >> 7;
  int ci = cols[e];
  float cntf = (float)nodeCnt[ci*16];
  float nel = fmaxf(cntf * (float)HH, 1.0f);
  float mu = sums[ci]/nel;
  float var = sums[16+ci]/nel - mu*mu;
  out[idx] = (hcBuf[idx]-mu)/sqrtf(var+EPSF);
}

extern "C" void kernel_launch(void* const* d_in, const int* in_sizes, int n_in,
                              void* d_out, int out_size, void* d_ws, size_t ws_size,
                              hipStream_t stream){
  const float* X    = (const float*)d_in[0];
  const float* W1   = (const float*)d_in[1];
  const float* b1   = (const float*)d_in[2];
  const float* ln_g = (const float*)d_in[3];
  const float* ln_b = (const float*)d_in[4];
  const float* W2   = (const float*)d_in[5];
  const float* b2   = (const float*)d_in[6];
  const float* Wl   = (const float*)d_in[7];
  const float* bl   = (const float*)d_in[8];
  const float* Wr   = (const float*)d_in[9];
  float* ws = (float*)d_ws;
  float* F      = ws + OFF_F;
  float* cnt    = ws + OFF_CNT;
  float* sums   = ws + OFF_SUMS;
  int*   nodeCnt= (int*)(ws + OFF_NCNT);
  int*   cols   = (int*)(ws + OFF_COLS);
  int*   ranks  = (int*)(ws + OFF_RANKS);
  float* fiSel  = ws + OFF_FISEL;
  int*   nodeList=(int*)(ws + OFF_NLIST);
  float* agg    = ws + OFF_AGG;
  float* hcBuf  = ws + OFF_HC;
  _Float16* hbase = (_Float16*)(ws + OFF_HALF);
  float* out    = (float*)d_out;

  k_fused  <<<dim3(FBLK), dim3(FTH), 0, stream>>>(X, W1, b1, ln_g, ln_b, W2, b2,
                                                  Wl, Wr, hbase, F, ws,
                                                  cols, ranks, fiSel);
  k_accF   <<<dim3(NN*KTOP/2 + 12), dim3(256), 0, stream>>>(X, cols, ranks, fiSel, F, cnt,
                                                            nodeCnt, nodeList);
  k_graph  <<<dim3(GCB,16), dim3(256), 0, stream>>>(F, cnt, agg);
  k_hc2    <<<dim3((NN/MT),16), dim3(512), 0, stream>>>(X, agg, hbase+HOFF_WLH,
                                                        hbase+HOFF_WRH, bl, ranks, fiSel,
                                                        nodeCnt, nodeList, hcBuf, sums);
  k_out    <<<dim3(NN*KTOP*HH/256), dim3(256), 0, stream>>>(hcBuf, cols, nodeCnt, sums, out);
}

// Round 15
// 151.494 us; speedup vs baseline: 1.0686x; 1.0686x over previous
//
#include <hip/hip_runtime.h>

#define NN 3072
#define CCC 16
#define HH 128
#define KTOP 4
#define NCLS 455   // C(15,3)
#define EPSF 1e-5f

// ---------------- ws layout (float offsets) ----------------
#define OFF_F       0
#define SZ_F        (16*NCLS*HH)            // 931840
#define OFF_CNT     (OFF_F + SZ_F)
#define SZ_CNT      (16*NCLS)
#define OFF_SUMS    (OFF_CNT + SZ_CNT)
#define SZ_SUMS     32
#define OFF_NCNT    (OFF_SUMS + SZ_SUMS)    // int nodeCnt[16*16]
#define SZ_NCNT     256
#define SMALL_ZERO  (SZ_CNT + SZ_SUMS + SZ_NCNT)  // cnt+sums+nodeCnt (zeroed by k_fused blk0)
#define OFF_COLS    (OFF_NCNT + SZ_NCNT)
#define SZ_E        (NN*KTOP)
#define OFF_RANKS   (OFF_COLS + SZ_E)
#define OFF_FISEL   (OFF_RANKS + SZ_E)
#define OFF_NLIST   (OFF_FISEL + SZ_E)
#define SZ_NLIST    (16*NN)
#define OFF_AGG     (OFF_NLIST + SZ_NLIST)
#define OFF_HC      (OFF_AGG + SZ_F)
#define SZ_HC       (NN*KTOP*HH)
#define OFF_HALF    (OFF_HC + SZ_HC)
#define HOFF_WLH    0
#define HOFF_WRH    262144

#define MT 64              // rows per block for k_hc2
#define FTH 768            // k_fused threads (12 waves)
#define FMT 192            // rows per block for k_fused (12 nodes)
#define FBLK (NN*CCC/FMT)  // 256 blocks = exactly 1 per CU (no tail imbalance)
#define GCP 8              // k_graph cols per block
#define GCB (HH/GCP)
#define W1P 132            // padded row stride (f16) for W1 LDS: 2-way bank aliasing only

typedef _Float16 h8 __attribute__((ext_vector_type(8)));
typedef float    f4 __attribute__((ext_vector_type(4)));

__device__ __forceinline__ int C2i(int x){ return x*(x-1)/2; }
__device__ __forceinline__ int C3i(int x){ return x*(x-1)*(x-2)/6; }

// ===== stage A+B fused: 768 thr / 192 rows per block, grid=256 (1 block/CU,
// ===== balanced). W1->LDS hi/lo cvt, logits MFMA, in-LDS topk/softmax.
// ===== Folded: F zeroing, Wl/Wr f16 cvt, small-zero (blk 0).
__global__ __launch_bounds__(FTH) void k_fused(const float* __restrict__ X,
    const float* __restrict__ W1,
    const float* __restrict__ b1, const float* __restrict__ ln_g,
    const float* __restrict__ ln_b, const float* __restrict__ W2,
    const float* __restrict__ b2,
    const float* __restrict__ Wl, const float* __restrict__ Wr,
    _Float16* __restrict__ hbase, float* __restrict__ F, float* __restrict__ ws,
    int* __restrict__ cols, int* __restrict__ ranks, float* __restrict__ fiSel){
  __shared__ _Float16 w1h_s[HH*W1P];
  __shared__ _Float16 w1l_s[HH*W1P];
  __shared__ float llog[FMT];
  int t = threadIdx.x;
  int w = t >> 6;              // wave 0..11 -> rows 16w..16w+15 (node w)
  int lane = t & 63;
  int l15 = lane & 15, quad = lane >> 4;
  int base = blockIdx.x * FMT;
  int mA = base + 16*w + l15;

  // ---- X rows first: HBM latency hides under the W1-cvt loop below ----
  const float* xrow = X + (size_t)mA*HH;
  float4 xu[4], xv[4];
  #pragma unroll
  for (int c=0;c<4;++c){
    xu[c] = *(const float4*)(xrow + c*32 + quad*8);
    xv[c] = *(const float4*)(xrow + c*32 + quad*8 + 4);
  }

  // ---- W1 -> LDS f16 hi/lo (same values as before; 22 iters/thread) ----
  for (int j = t; j < HH*HH; j += FTH){
    int r = j >> 7, c0 = j & 127;
    float x = W1[j];
    _Float16 h = (_Float16)x;
    w1h_s[r*W1P + c0] = h;
    w1l_s[r*W1P + c0] = (_Float16)(x - (float)h);
  }

  // ---- folded housekeeping: zero F + cvt Wl/Wr + (blk 0) small zeros ----
  {
    f4 z4 = (f4){0.f,0.f,0.f,0.f};
    for (int i = blockIdx.x*FTH + t; i < SZ_F/4; i += FBLK*FTH)
      *(f4*)(F + (size_t)i*4) = z4;
    for (int i = blockIdx.x*FTH + t; i < 2*262144; i += FBLK*FTH){
      if (i < 262144) hbase[HOFF_WLH + i] = (_Float16)Wl[i];
      else            hbase[HOFF_WRH + (i-262144)] = (_Float16)Wr[i-262144];
    }
    if (blockIdx.x == 0)
      for (int i = t; i < SMALL_ZERO; i += FTH) ws[OFF_CNT + i] = 0.f;
  }

  // ---- phase 1: z=relu(X@W1^T+b1); LN; logit=zn.W2+b2 (identical math) ----
  h8 ah[4], al[4];
  #pragma unroll
  for (int c=0;c<4;++c){
    float xvv[8] = {xu[c].x,xu[c].y,xu[c].z,xu[c].w,xv[c].x,xv[c].y,xv[c].z,xv[c].w};
    #pragma unroll
    for (int j=0;j<8;++j){
      _Float16 hi = (_Float16)xvv[j];
      ah[c][j] = hi;
      al[c][j] = (_Float16)(xvv[j] - (float)hi);
    }
  }
  __syncthreads();   // W1 LDS ready

  f4 acc[8];
  #pragma unroll
  for (int nt=0;nt<8;++nt) acc[nt] = (f4){0.f,0.f,0.f,0.f};

  #pragma unroll
  for (int c=0;c<4;++c){
    #pragma unroll
    for (int nt=0;nt<8;++nt){
      int o = nt*16 + l15;
      h8 bh  = *(const h8*)(w1h_s + o*W1P + c*32 + quad*8);
      h8 bl_ = *(const h8*)(w1l_s + o*W1P + c*32 + quad*8);
      acc[nt] = __builtin_amdgcn_mfma_f32_16x16x32_f16(ah[c], bh,  acc[nt], 0,0,0);
      acc[nt] = __builtin_amdgcn_mfma_f32_16x16x32_f16(al[c], bh,  acc[nt], 0,0,0);
      acc[nt] = __builtin_amdgcn_mfma_f32_16x16x32_f16(ah[c], bl_, acc[nt], 0,0,0);
      acc[nt] = __builtin_amdgcn_mfma_f32_16x16x32_f16(al[c], bl_, acc[nt], 0,0,0);
    }
  }

  float bv[8], gv[8], lv[8], wv[8];
  #pragma unroll
  for (int nt=0;nt<8;++nt){
    int o = nt*16 + l15;
    bv[nt]=b1[o]; gv[nt]=ln_g[o]; lv[nt]=ln_b[o]; wv[nt]=W2[o];
  }
  float b2v = b2[0];
  #pragma unroll
  for (int r=0;r<4;++r){
    float z[8];
    float s1=0.f, s2=0.f;
    #pragma unroll
    for (int nt=0;nt<8;++nt){
      float zz = acc[nt][r] + bv[nt];
      zz = zz>0.f ? zz : 0.f;
      z[nt] = zz; s1 += zz; s2 += zz*zz;
    }
    #pragma unroll
    for (int m=1;m<16;m<<=1){ s1 += __shfl_xor(s1,m); s2 += __shfl_xor(s2,m); }
    float mu = s1/(float)HH;
    float var = s2/(float)HH - mu*mu;
    float rs = 1.0f/sqrtf(var+EPSF);
    float s3 = 0.f;
    #pragma unroll
    for (int nt=0;nt<8;++nt){
      float zn = (z[nt]-mu)*rs*gv[nt] + lv[nt];
      s3 += zn*wv[nt];
    }
    #pragma unroll
    for (int m=1;m<16;m<<=1) s3 += __shfl_xor(s3,m);
    if (l15 == 0) llog[16*w + quad*4 + r] = s3 + b2v;
  }
  __syncthreads();

  // ---- phase 2: topk/softmax per node (threads 0..11), plain stores only ----
  if (t < FMT/16){
    int n = blockIdx.x*(FMT/16) + t;
    float l[CCC];
    #pragma unroll
    for (int c=0;c<CCC;++c) l[c] = llog[t*16+c];
    unsigned mask = 0;
    #pragma unroll
    for (int k=0;k<KTOP;++k){
      float best = -3e38f; int bi = 0;
      #pragma unroll
      for (int c=0;c<CCC;++c){
        bool taken = (mask>>c)&1u;
        if (!taken && l[c] > best){ best = l[c]; bi = c; }
      }
      mask |= 1u<<bi;
    }
    float m = -3e38f;
    #pragma unroll
    for (int c=0;c<CCC;++c) m = l[c]>m ? l[c] : m;
    float s = 0.f;
    #pragma unroll
    for (int c=0;c<CCC;++c) s += expf(l[c]-m);
    float inv = 1.0f/s;
    unsigned m2 = mask;
    for (int j=0;j<KTOP;++j){
      int ci = __ffs(m2)-1; m2 &= m2-1u;
      unsigned rest = mask & ~(1u<<ci);
      int v[3]; unsigned r2 = rest;
      #pragma unroll
      for (int q=0;q<3;++q){ int col = __ffs(r2)-1; r2 &= r2-1u; v[q] = col - (col>ci ? 1:0); }
      int rank = C3i(v[2]) + C2i(v[1]) + v[0];
      int e4 = n*KTOP + j;
      cols[e4] = ci; ranks[e4] = rank; fiSel[e4] = expf(l[ci]-m)*inv;
    }
  }
}

// ===== stage C: class feature sums (high-TLP atomics, 6144 blocks) + nodeList
// ===== build in 12 extra blocks (merged k_nlist; R10-proven) =====
__global__ __launch_bounds__(256) void k_accF(const float* __restrict__ X,
    const int* __restrict__ cols, const int* __restrict__ ranks,
    const float* __restrict__ fiSel, float* __restrict__ F, float* __restrict__ cnt,
    int* __restrict__ nodeCnt, int* __restrict__ nodeList){
  __shared__ int lcnt[CCC];
  __shared__ int lbase[CCC];
  int t = threadIdx.x;
  if (blockIdx.x < NN*KTOP/2){
    int e = blockIdx.x*2 + (t>>7);
    int h = t & 127;
    int ci = cols[e], rank = ranks[e];
    float fi = fiSel[e];
    int n = e >> 2;
    float v = X[(n*CCC+ci)*HH + h] * fi;
    atomicAdd(&F[(ci*NCLS+rank)*HH + h], v);
    if (h==0) atomicAdd(&cnt[ci*NCLS+rank], 1.0f);
  } else {
    int nb = blockIdx.x - NN*KTOP/2;   // 0..11
    if (t < CCC) lcnt[t] = 0;
    __syncthreads();
    int n = nb*256 + t;
    int mycis[KTOP], mypos[KTOP];
    #pragma unroll
    for (int j=0;j<KTOP;++j){
      int ci = cols[n*KTOP+j];
      mycis[j] = ci;
      mypos[j] = atomicAdd(&lcnt[ci], 1);
    }
    __syncthreads();
    if (t < CCC) lbase[t] = atomicAdd(&nodeCnt[t*16], lcnt[t]);
    __syncthreads();
    #pragma unroll
    for (int j=0;j<KTOP;++j){
      int ci = mycis[j];
      nodeList[ci*NN + lbase[ci] + mypos[j]] = n*KTOP + j;
    }
  }
}

// ====== stage D: pairs + singles + degrees + inclusion-exclusion agg (R1-proven) ======
__global__ __launch_bounds__(256) void k_graph(const float* __restrict__ F,
    const float* __restrict__ cnt, float* __restrict__ agg){
  int cb = blockIdx.x, ci = blockIdx.y, t = threadIdx.x;
  __shared__ float cntl[NCLS];
  __shared__ float PcS[105], UcS[15];
  __shared__ int   abcs[NCLS];   // a | b<<5 | c<<10
  __shared__ int   prs[NCLS];    // pab | pac<<10 | pbc<<20
  __shared__ float Fl[NCLS*GCP];
  __shared__ float P[105*GCP];
  __shared__ float U[15*GCP];
  const float* Fc = F + (size_t)ci*NCLS*HH + cb*GCP;

  for (int i=t; i<NCLS*2; i+=256){
    int r = i>>1, hf = i&1;
    float4 v = *(const float4*)(Fc + (size_t)r*HH + hf*4);
    *(float4*)(&Fl[r*GCP + hf*4]) = v;
  }
  for (int r=t; r<NCLS; r+=256){
    cntl[r] = cnt[ci*NCLS+r];
    int c=2; while (c<14 && C3i(c+1)<=r) c++;
    int rem = r - C3i(c);
    int b=1; while (b<c-1 && C2i(b+1)<=rem) b++;
    int a = rem - C2i(b);
    abcs[r] = a | (b<<5) | (c<<10);
    prs[r] = (C2i(b)+a) | ((C2i(c)+a)<<10) | ((C2i(c)+b)<<20);
  }
  __syncthreads();
  if (t<105){
    int pb=1; while (pb<14 && C2i(pb+1)<=t) pb++;
    int pa = t - C2i(pb);
    float s=0.f;
    #pragma unroll
    for (int z=0;z<15;++z){
      if (z==pa||z==pb) continue;
      int lo,mid,hi;
      if (z<pa){lo=z;mid=pa;hi=pb;} else if (z<pb){lo=pa;mid=z;hi=pb;} else {lo=pa;mid=pb;hi=z;}
      s += cntl[C3i(hi)+C2i(mid)+lo];
    }
    PcS[t]=s;
  }
  __syncthreads();
  if (t<15){
    float s=0.f;
    #pragma unroll
    for (int y=0;y<15;++y){
      if (y==t) continue;
      int lo = t<y?t:y, hi = t<y?y:t;
      s += PcS[C2i(hi)+lo];
    }
    UcS[t]=0.5f*s;
  }
  __syncthreads();
  for (int idx=t; idx<105*GCP; idx+=256){
    int p = idx/GCP, col = idx&(GCP-1);
    int pb=1; while (pb<14 && C2i(pb+1)<=p) pb++;
    int pa = p - C2i(pb);
    float s=0.f;
    #pragma unroll
    for (int z=0;z<15;++z){
      if (z==pa||z==pb) continue;
      int lo,mid,hi;
      if (z<pa){lo=z;mid=pa;hi=pb;} else if (z<pb){lo=pa;mid=z;hi=pb;} else {lo=pa;mid=pb;hi=z;}
      s += Fl[(C3i(hi)+C2i(mid)+lo)*GCP + col];
    }
    P[idx]=s;
  }
  __syncthreads();
  for (int idx=t; idx<15*GCP; idx+=256){
    int x = idx/GCP, col = idx&(GCP-1);
    float s=0.f;
    #pragma unroll
    for (int y=0;y<15;++y){
      if (y==x) continue;
      int lo = x<y?x:y, hi = x<y?y:x;
      s += P[(C2i(hi)+lo)*GCP + col];
    }
    U[idx]=0.5f*s;
  }
  __syncthreads();
  for (int idx=t; idx<NCLS*GCP; idx+=256){
    int r = idx/GCP, col = idx&(GCP-1);
    int v1=abcs[r]; int a=v1&31,b=(v1>>5)&31,c=(v1>>10)&31;
    int v2=prs[r];  int pab=v2&1023,pac=(v2>>10)&1023,pbc=(v2>>20)&1023;
    float deg = UcS[a]+UcS[b]+UcS[c]-PcS[pab]-PcS[pac]-PcS[pbc]+cntl[r];
    float invd = 1.0f/fmaxf(deg,1.0f);
    float v = U[a*GCP+col]+U[b*GCP+col]+U[c*GCP+col]
            - P[pab*GCP+col]-P[pac*GCP+col]-P[pbc*GCP+col]
            + Fl[r*GCP+col];
    agg[(size_t)ci*NCLS*HH + (size_t)r*HH + cb*GCP + col] = v*invd;
  }
}

// ===== stage E (merged E1+E2): hc = relu(agg[rank]@Wl^T + bl + fi*X @ Wr^T) =====
__global__ __launch_bounds__(256) void k_hc2(const float* __restrict__ X,
    const float* __restrict__ agg,
    const _Float16* __restrict__ Wlh, const _Float16* __restrict__ Wrh,
    const float* __restrict__ bl,
    const int* __restrict__ ranks, const float* __restrict__ fiSel,
    const int* __restrict__ nodeCnt, const int* __restrict__ nodeList,
    float* __restrict__ hcBuf, float* __restrict__ sums){
  int ci = blockIdx.y;
  int cntc = nodeCnt[ci*16];
  int base = blockIdx.x * MT;
  if (base >= cntc) return;
  __shared__ float rb[8];
  int t = threadIdx.x;
  int w = t >> 6;
  int lane = t & 63;
  int l15 = lane & 15, quad = lane >> 4;

  int pA = base + 16*w + l15;
  float fi = 0.f; int nA = 0; int rkA = -1;
  if (pA < cntc){
    int e = nodeList[ci*NN + pA];
    fi = fiSel[e]; nA = e >> 2; rkA = ranks[e];
  }
  // A-operand 1: fi * X[nA, ci, :]
  const float* xrow = X + ((size_t)nA*CCC + ci)*HH;
  h8 af[4];
  #pragma unroll
  for (int c=0;c<4;++c){
    float4 u = *(const float4*)(xrow + c*32 + quad*8);
    float4 v = *(const float4*)(xrow + c*32 + quad*8 + 4);
    float xv[8] = {u.x,u.y,u.z,u.w,v.x,v.y,v.z,v.w};
    #pragma unroll
    for (int j=0;j<8;++j) af[c][j] = (_Float16)(xv[j]*fi);
  }
  // A-operand 2: agg[ci, rank(pA), :]  (zero for inactive rows)
  h8 ag[4];
  if (rkA >= 0){
    const float* arow = agg + ((size_t)ci*NCLS + rkA)*HH;
    #pragma unroll
    for (int c=0;c<4;++c){
      float4 u = *(const float4*)(arow + c*32 + quad*8);
      float4 v = *(const float4*)(arow + c*32 + quad*8 + 4);
      float xv[8] = {u.x,u.y,u.z,u.w,v.x,v.y,v.z,v.w};
      #pragma unroll
      for (int j=0;j<8;++j) ag[c][j] = (_Float16)xv[j];
    }
  } else {
    #pragma unroll
    for (int c=0;c<4;++c) ag[c] = (h8){0,0,0,0,0,0,0,0};
  }

  f4 acc[8];
  #pragma unroll
  for (int nt=0;nt<8;++nt) acc[nt] = (f4){0.f,0.f,0.f,0.f};

  const _Float16* WcR = Wrh + (size_t)ci*HH*HH;
  const _Float16* WcL = Wlh + (size_t)ci*HH*HH;
  #pragma unroll
  for (int c=0;c<4;++c){
    #pragma unroll
    for (int nt=0;nt<8;++nt){
      int o = nt*16 + l15;
      h8 br = *(const h8*)(WcR + (size_t)o*HH + c*32 + quad*8);
      h8 blf= *(const h8*)(WcL + (size_t)o*HH + c*32 + quad*8);
      acc[nt] = __builtin_amdgcn_mfma_f32_16x16x32_f16(af[c], br,  acc[nt], 0,0,0);
      acc[nt] = __builtin_amdgcn_mfma_f32_16x16x32_f16(ag[c], blf, acc[nt], 0,0,0);
    }
  }

  float s1 = 0.f, s2 = 0.f;
  #pragma unroll
  for (int r=0;r<4;++r){
    int pD = base + 16*w + quad*4 + r;
    int e2 = -1;
    if (pD < cntc) e2 = nodeList[ci*NN + pD];
    if (e2 >= 0){
      float* drow = hcBuf + (size_t)e2*HH;
      #pragma unroll
      for (int nt=0;nt<8;++nt){
        int o = nt*16 + l15;
        float vv = acc[nt][r] + bl[ci*HH + o];
        vv = vv>0.f ? vv : 0.f;
        drow[o] = vv;
        s1 += vv; s2 += vv*vv;
      }
    }
  }
  #pragma unroll
  for (int m=1;m<64;m<<=1){ s1 += __shfl_xor(s1,m); s2 += __shfl_xor(s2,m); }
  if (lane == 0){ rb[w] = s1; rb[4+w] = s2; }
  __syncthreads();
  if (t==0){
    atomicAdd(&sums[ci],    rb[0]+rb[1]+rb[2]+rb[3]);
    atomicAdd(&sums[16+ci], rb[4]+rb[5]+rb[6]+rb[7]);
  }
}

// ========== stage F: masked mean/var normalize, write output ==========
__global__ __launch_bounds__(256) void k_out(const float* __restrict__ hcBuf,
    const int* __restrict__ cols, const int* __restrict__ nodeCnt,
    const float* __restrict__ sums, float* __restrict__ out){
  int idx = blockIdx.x*256 + threadIdx.x;
  int e = idx >> 7;
  int ci = cols[e];
  float cntf = (float)nodeCnt[ci*16];
  float nel = fmaxf(cntf * (float)HH, 1.0f);
  float mu = sums[ci]/nel;
  float var = sums[16+ci]/nel - mu*mu;
  out[idx] = (hcBuf[idx]-mu)/sqrtf(var+EPSF);
}

extern "C" void kernel_launch(void* const* d_in, const int* in_sizes, int n_in,
                              void* d_out, int out_size, void* d_ws, size_t ws_size,
                              hipStream_t stream){
  const float* X    = (const float*)d_in[0];
  const float* W1   = (const float*)d_in[1];
  const float* b1   = (const float*)d_in[2];
  const float* ln_g = (const float*)d_in[3];
  const float* ln_b = (const float*)d_in[4];
  const float* W2   = (const float*)d_in[5];
  const float* b2   = (const float*)d_in[6];
  const float* Wl   = (const float*)d_in[7];
  const float* bl   = (const float*)d_in[8];
  const float* Wr   = (const float*)d_in[9];
  float* ws = (float*)d_ws;
  float* F      = ws + OFF_F;
  float* cnt    = ws + OFF_CNT;
  float* sums   = ws + OFF_SUMS;
  int*   nodeCnt= (int*)(ws + OFF_NCNT);
  int*   cols   = (int*)(ws + OFF_COLS);
  int*   ranks  = (int*)(ws + OFF_RANKS);
  float* fiSel  = ws + OFF_FISEL;
  int*   nodeList=(int*)(ws + OFF_NLIST);
  float* agg    = ws + OFF_AGG;
  float* hcBuf  = ws + OFF_HC;
  _Float16* hbase = (_Float16*)(ws + OFF_HALF);
  float* out    = (float*)d_out;

  k_fused  <<<dim3(FBLK), dim3(FTH), 0, stream>>>(X, W1, b1, ln_g, ln_b, W2, b2,
                                                  Wl, Wr, hbase, F, ws,
                                                  cols, ranks, fiSel);
  k_accF   <<<dim3(NN*KTOP/2 + 12), dim3(256), 0, stream>>>(X, cols, ranks, fiSel, F, cnt,
                                                            nodeCnt, nodeList);
  k_graph  <<<dim3(GCB,16), dim3(256), 0, stream>>>(F, cnt, agg);
  k_hc2    <<<dim3((NN/MT),16), dim3(256), 0, stream>>>(X, agg, hbase+HOFF_WLH,
                                                        hbase+HOFF_WRH, bl, ranks, fiSel,
                                                        nodeCnt, nodeList, hcBuf, sums);
  k_out    <<<dim3(NN*KTOP*HH/256), dim3(256), 0, stream>>>(hcBuf, cols, nodeCnt, sums, out);
}